// Round 1
// baseline (1738.032 us; speedup 1.0000x reference)
//
#include <hip/hip_runtime.h>
#include <hip/hip_bf16.h>
#include <math.h>

#define HWn 65536
#define Hh 256
#define Wd 256
#define Bb 2
#define Cc 64
#define NHh 8
#define HIDc 170

typedef __hip_bfloat16 bf16;

// ---------- zero small scratch ----------
__global__ void zero_k(float* p, int n) {
    for (int i = threadIdx.x; i < n; i += 256) p[i] = 0.f;
}

// ---------- per-pixel channel LayerNorm (64 ch), f32 in -> bf16 out ----------
__global__ void ln_ch_k(const float* __restrict__ x, const float* __restrict__ w,
                        const float* __restrict__ bia, bf16* __restrict__ out) {
    int idx = blockIdx.x * 256 + threadIdx.x;          // 0..B*HW
    int b = idx >> 16;
    int p = idx & 65535;
    const float* xp = x + (size_t)b * Cc * HWn + p;
    float f[64];
    float s = 0.f;
#pragma unroll
    for (int c = 0; c < 64; c++) { f[c] = xp[(size_t)c * HWn]; s += f[c]; }
    float mu = s * (1.f / 64.f);
    float s2 = 0.f;
#pragma unroll
    for (int c = 0; c < 64; c++) { float d = f[c] - mu; s2 += d * d; }
    float inv = rsqrtf(s2 * (1.f / 64.f) + 1e-5f);
    bf16* op = out + (size_t)b * Cc * HWn + p;
#pragma unroll
    for (int c = 0; c < 64; c++)
        op[(size_t)c * HWn] = __float2bfloat16((f[c] - mu) * inv * w[c] + bia[c]);
}

// ---------- 1x1 conv, 64 in-ch -> co_count out-ch (weights in LDS) ----------
__global__ void conv1x1_from64(const bf16* __restrict__ in, const float* __restrict__ w,
                               int co_count, int co_total, int co_start,
                               bf16* __restrict__ out) {
    extern __shared__ float ws[];
    for (int i = threadIdx.x; i < co_count * 64; i += 256) ws[i] = w[i];
    __syncthreads();
    int idx = blockIdx.x * 256 + threadIdx.x;
    int b = idx >> 16;
    int p = idx & 65535;
    const bf16* ip = in + (size_t)b * 64 * HWn + p;
    float xin[64];
#pragma unroll
    for (int c = 0; c < 64; c++) xin[c] = __bfloat162float(ip[(size_t)c * HWn]);
    bf16* op = out + ((size_t)b * co_total + co_start) * HWn + p;
    for (int o = 0; o < co_count; ++o) {
        const float* wr = ws + o * 64;
        float acc = 0.f;
#pragma unroll
        for (int c = 0; c < 64; c++) acc = fmaf(wr[c], xin[c], acc);
        op[(size_t)o * HWn] = __float2bfloat16(acc);
    }
}

// ---------- depthwise 3x3, SAME zero pad, bf16 -> bf16 ----------
__global__ void dwconv3_k(const bf16* __restrict__ in, const float* __restrict__ w,
                          int CH, bf16* __restrict__ out) {
    int rowid = blockIdx.x;            // (b*CH+ch)*H + y
    int y = rowid & (Hh - 1);
    int img = rowid >> 8;              // b*CH+ch
    int ch = img % CH;
    int xx = threadIdx.x;
    const bf16* base = in + ((size_t)img * Hh) * Wd;
    float wv[9];
#pragma unroll
    for (int i = 0; i < 9; i++) wv[i] = w[ch * 9 + i];
    float acc = 0.f;
#pragma unroll
    for (int dy = -1; dy <= 1; ++dy) {
        int ys = y + dy;
        if (ys < 0 || ys >= Hh) continue;
        const bf16* r = base + (size_t)ys * Wd;
#pragma unroll
        for (int dx = -1; dx <= 1; ++dx) {
            int xs = xx + dx;
            if (xs < 0 || xs >= Wd) continue;
            acc = fmaf(wv[(dy + 1) * 3 + (dx + 1)], __bfloat162float(r[xs]), acc);
        }
    }
    out[(size_t)rowid * Wd + xx] = __float2bfloat16(acc);
}

// ---------- row sum-of-squares for l2norm (channels 0..127 of a 192-ch tensor) ----------
__global__ void rownorm_sq(const bf16* __restrict__ src, float* __restrict__ nsq) {
    int row = blockIdx.x;              // b*128 + ch
    int b = row >> 7;
    int ch = row & 127;
    const bf16* p = src + ((size_t)b * 192 + ch) * HWn;
    int nchunks = gridDim.y;
    int per = HWn / nchunks;
    int n0 = blockIdx.y * per;
    float s = 0.f;
    for (int i = n0 + threadIdx.x; i < n0 + per; i += 256) {
        float v = __bfloat162float(p[i]);
        s = fmaf(v, v, s);
    }
#pragma unroll
    for (int m = 1; m < 64; m <<= 1) s += __shfl_xor(s, m);
    if ((threadIdx.x & 63) == 0) atomicAdd(&nsq[row], s);
}

// ---------- attention dot products: G[which][b][h][c][d] = sum_n a[c,n]*k[d,n] ----------
__global__ void attn_dots(const bf16* __restrict__ txd, const bf16* __restrict__ tyd,
                          float* __restrict__ G) {
    int which = blockIdx.z;            // 0: q1 (y) . k (x)   1: q (x) . k1 (y)
    int bh = blockIdx.y;
    int b = bh >> 3;
    int h = bh & 7;
    const bf16* Aq = (which == 0 ? tyd : txd) + ((size_t)b * 192 + h * 8) * HWn;
    const bf16* Bk = (which == 0 ? txd : tyd) + ((size_t)b * 192 + 64 + h * 8) * HWn;
    float acc[8][8];
#pragma unroll
    for (int c = 0; c < 8; c++)
#pragma unroll
        for (int d = 0; d < 8; d++) acc[c][d] = 0.f;
    int per = HWn / gridDim.x;
    int n0 = blockIdx.x * per;
    for (int n = n0 + threadIdx.x; n < n0 + per; n += 256) {
        float av[8], bv[8];
#pragma unroll
        for (int i = 0; i < 8; i++) av[i] = __bfloat162float(Aq[(size_t)i * HWn + n]);
#pragma unroll
        for (int i = 0; i < 8; i++) bv[i] = __bfloat162float(Bk[(size_t)i * HWn + n]);
#pragma unroll
        for (int c = 0; c < 8; c++)
#pragma unroll
            for (int d = 0; d < 8; d++) acc[c][d] = fmaf(av[c], bv[d], acc[c][d]);
    }
    float* Gp = G + (((size_t)which * Bb + b) * 8 + h) * 64;
#pragma unroll
    for (int c = 0; c < 8; c++)
#pragma unroll
        for (int d = 0; d < 8; d++) {
            float s = acc[c][d];
#pragma unroll
            for (int m = 1; m < 64; m <<= 1) s += __shfl_xor(s, m);
            if ((threadIdx.x & 63) == 0) atomicAdd(&Gp[c * 8 + d], s);
        }
}

// ---------- tiny softmax with l2norm scaling and temperature ----------
__global__ void attn_softmax(const float* __restrict__ G, const float* __restrict__ nsq,
                             const float* __restrict__ temp, float* __restrict__ A) {
    int t = threadIdx.x;               // 256 rows: (which,b,h,c)
    int which = t >> 7;
    int b = (t >> 6) & 1;
    int h = (t >> 3) & 7;
    int c = t & 7;
    const float* nX = nsq;             // x-side (txd) sumsq, rows b*128+ch
    const float* nY = nsq + 256;       // y-side (tyd)
    const float* Gp = G + ((((size_t)which * Bb + b) * 8 + h) * 8 + c) * 8;
    float na = (which == 0 ? nY : nX)[b * 128 + h * 8 + c];
    float an = fmaxf(sqrtf(na), 1e-12f);
    float tm = temp[h];
    float vals[8];
    float mx = -1e30f;
#pragma unroll
    for (int d = 0; d < 8; d++) {
        float nb = (which == 0 ? nX : nY)[b * 128 + 64 + h * 8 + d];
        float bn = fmaxf(sqrtf(nb), 1e-12f);
        float v = Gp[d] / (an * bn) * tm;
        vals[d] = v;
        mx = fmaxf(mx, v);
    }
    float se = 0.f;
#pragma unroll
    for (int d = 0; d < 8; d++) { vals[d] = expf(vals[d] - mx); se += vals[d]; }
    float inv = 1.f / se;
    float* Ap = A + ((((size_t)which * Bb + b) * 8 + h) * 8 + c) * 8;
#pragma unroll
    for (int d = 0; d < 8; d++) Ap[d] = vals[d] * inv;
}

// ---------- cross attention output + residual: out = x + A1@v + A2@v1 ----------
__global__ void cross_add(const float* __restrict__ x, const bf16* __restrict__ txd,
                          const bf16* __restrict__ tyd, const float* __restrict__ A,
                          float* __restrict__ out) {
    int bh = blockIdx.y;
    int b = bh >> 3;
    int h = bh & 7;
    __shared__ float a1[64], a2[64];
    int t = threadIdx.x;
    if (t < 64) a1[t] = A[(((size_t)0 * Bb + b) * 8 + h) * 64 + t];
    else if (t < 128) a2[t - 64] = A[(((size_t)1 * Bb + b) * 8 + h) * 64 + (t - 64)];
    __syncthreads();
    int n = blockIdx.x * 256 + t;
    float v[8], v1[8];
#pragma unroll
    for (int d = 0; d < 8; d++) {
        v[d]  = __bfloat162float(txd[((size_t)b * 192 + 128 + h * 8 + d) * HWn + n]);
        v1[d] = __bfloat162float(tyd[((size_t)b * 192 + 128 + h * 8 + d) * HWn + n]);
    }
#pragma unroll
    for (int c = 0; c < 8; c++) {
        size_t oi = ((size_t)b * 64 + h * 8 + c) * HWn + n;
        float s = x[oi];
#pragma unroll
        for (int d = 0; d < 8; d++)
            s += a1[c * 8 + d] * v[d] + a2[c * 8 + d] * v1[d];
        out[oi] = s;
    }
}

// ---------- GDFN output: out += W_out @ (gelu(g1) * g2) ----------
__global__ void gdfn_out_k(const bf16* __restrict__ gd, const float* __restrict__ w,
                           float* __restrict__ out) {
    extern __shared__ float ws[];      // [64][170]
    for (int i = threadIdx.x; i < 64 * HIDc; i += 256) ws[i] = w[i];
    __syncthreads();
    int idx = blockIdx.x * 256 + threadIdx.x;
    int b = idx >> 16;
    int p = idx & 65535;
    const bf16* g1 = gd + (size_t)b * (2 * HIDc) * HWn + p;
    const bf16* g2 = g1 + (size_t)HIDc * HWn;
    float acc[64];
#pragma unroll
    for (int c = 0; c < 64; c++) acc[c] = 0.f;
    for (int hid = 0; hid < HIDc; ++hid) {
        float a = __bfloat162float(g1[(size_t)hid * HWn]);
        float g = __bfloat162float(g2[(size_t)hid * HWn]);
        float t = a * 0.5f * (1.f + erff(a * 0.70710678118654752f)) * g;
#pragma unroll
        for (int c = 0; c < 64; c++) acc[c] = fmaf(ws[c * HIDc + hid], t, acc[c]);
    }
    float* op = out + (size_t)b * 64 * HWn + p;
#pragma unroll
    for (int c = 0; c < 64; c++) op[(size_t)c * HWn] += acc[c];
}

extern "C" void kernel_launch(void* const* d_in, const int* in_sizes, int n_in,
                              void* d_out, int out_size, void* d_ws, size_t ws_size,
                              hipStream_t stream) {
    const float* x        = (const float*)d_in[0];
    const float* y        = (const float*)d_in[1];
    const float* ln11_w   = (const float*)d_in[2];
    const float* ln11_b   = (const float*)d_in[3];
    const float* ln12_w   = (const float*)d_in[4];
    const float* ln12_b   = (const float*)d_in[5];
    const float* ln2_w    = (const float*)d_in[6];
    const float* ln2_b    = (const float*)d_in[7];
    const float* qkv_w    = (const float*)d_in[8];
    const float* qkv_dw   = (const float*)d_in[9];
    const float* temp     = (const float*)d_in[10];
    const float* gdfn_in_w  = (const float*)d_in[11];
    const float* gdfn_dw    = (const float*)d_in[12];
    const float* gdfn_out_w = (const float*)d_in[13];
    float* out = (float*)d_out;

    char* ws = (char*)d_ws;
    // small scratch
    float* nsq  = (float*)ws;          // 512 floats (256 x-side, 256 y-side)
    float* G    = nsq + 512;           // 2048 floats
    float* Amat = G + 2048;            // 2048 floats
    size_t base = 18432;               // 4608 floats, 256B aligned
    bf16* xn  = (bf16*)(ws + base);                       // 8,388,608 elems
    bf16* yn  = xn + (size_t)8388608;
    bf16* tx  = (bf16*)(ws + base + (size_t)33554432);    // 25,165,824 elems
    bf16* txd = tx + (size_t)25165824;
    bf16* tyd = txd + (size_t)25165824;
    bf16* g   = tx;                                       // reuse (44,564,480 elems)
    bf16* gd  = tx + (size_t)44564480;

    const int NPIXB = 512;             // B*HW/256

    zero_k<<<1, 256, 0, stream>>>(nsq, 512 + 2048);

    ln_ch_k<<<NPIXB, 256, 0, stream>>>(x, ln11_w, ln11_b, xn);
    ln_ch_k<<<NPIXB, 256, 0, stream>>>(y, ln12_w, ln12_b, yn);

    conv1x1_from64<<<NPIXB, 256, 192 * 64 * 4, stream>>>(xn, qkv_w, 192, 192, 0, tx);
    dwconv3_k<<<Bb * 192 * Hh, 256, 0, stream>>>(tx, qkv_dw, 192, txd);
    conv1x1_from64<<<NPIXB, 256, 192 * 64 * 4, stream>>>(yn, qkv_w, 192, 192, 0, tx);
    dwconv3_k<<<Bb * 192 * Hh, 256, 0, stream>>>(tx, qkv_dw, 192, tyd);

    rownorm_sq<<<dim3(256, 16), 256, 0, stream>>>(txd, nsq);
    rownorm_sq<<<dim3(256, 16), 256, 0, stream>>>(tyd, nsq + 256);

    attn_dots<<<dim3(32, 16, 2), 256, 0, stream>>>(txd, tyd, G);
    attn_softmax<<<1, 256, 0, stream>>>(G, nsq, temp, Amat);

    cross_add<<<dim3(256, 16), 256, 0, stream>>>(x, txd, tyd, Amat, out);

    ln_ch_k<<<NPIXB, 256, 0, stream>>>(out, ln2_w, ln2_b, xn);   // xn2 reuses xn
    conv1x1_from64<<<NPIXB, 256, 170 * 64 * 4, stream>>>(xn, gdfn_in_w, 170, 340, 0, g);
    conv1x1_from64<<<NPIXB, 256, 170 * 64 * 4, stream>>>(xn, gdfn_in_w + 170 * 64, 170, 340, 170, g);
    dwconv3_k<<<Bb * 340 * Hh, 256, 0, stream>>>(g, gdfn_dw, 340, gd);
    gdfn_out_k<<<NPIXB, 256, 64 * HIDc * 4, stream>>>(gd, gdfn_out_w, out);
}

// Round 2
// 1293.203 us; speedup vs baseline: 1.3440x; 1.3440x over previous
//
#include <hip/hip_runtime.h>
#include <hip/hip_bf16.h>
#include <math.h>

#define HWn 65536
#define Hh 256
#define Wd 256
#define Bb 2
#define Cc 64
#define NHh 8
#define HIDc 170

typedef __hip_bfloat16 bf16;
typedef __attribute__((ext_vector_type(8))) short short8;

__device__ inline float b2f(short u) {
    unsigned int x = ((unsigned int)(unsigned short)u) << 16;
    return __uint_as_float(x);
}
__device__ inline short f2b(float f) {
    __hip_bfloat16 h = __float2bfloat16(f);
    return *reinterpret_cast<short*>(&h);
}

// ---------- zero small scratch ----------
__global__ void zero_k(float* p, int n) {
    for (int i = threadIdx.x; i < n; i += 256) p[i] = 0.f;
}

// ---------- per-pixel channel LayerNorm (64 ch), f32 in -> bf16 out ----------
__global__ void ln_ch_k(const float* __restrict__ x, const float* __restrict__ w,
                        const float* __restrict__ bia, bf16* __restrict__ out) {
    int idx = blockIdx.x * 256 + threadIdx.x;
    int b = idx >> 16;
    int p = idx & 65535;
    const float* xp = x + (size_t)b * Cc * HWn + p;
    float f[64];
    float s = 0.f;
#pragma unroll
    for (int c = 0; c < 64; c++) { f[c] = xp[(size_t)c * HWn]; s += f[c]; }
    float mu = s * (1.f / 64.f);
    float s2 = 0.f;
#pragma unroll
    for (int c = 0; c < 64; c++) { float d = f[c] - mu; s2 += d * d; }
    float inv = rsqrtf(s2 * (1.f / 64.f) + 1e-5f);
    bf16* op = out + (size_t)b * Cc * HWn + p;
#pragma unroll
    for (int c = 0; c < 64; c++)
        op[(size_t)c * HWn] = __float2bfloat16((f[c] - mu) * inv * w[c] + bia[c]);
}

// ---------- 1x1 conv, 64 in -> co_per out per y-group (weights in LDS) ----------
__global__ void conv1x1_g(const bf16* __restrict__ in, const float* __restrict__ w,
                          int co_per, int co_total, bf16* __restrict__ out) {
    extern __shared__ float ws[];
    int co_start = blockIdx.y * co_per;
    for (int i = threadIdx.x; i < co_per * 64; i += 256) ws[i] = w[co_start * 64 + i];
    __syncthreads();
    int idx = blockIdx.x * 256 + threadIdx.x;
    int b = idx >> 16;
    int p = idx & 65535;
    const bf16* ip = in + (size_t)b * 64 * HWn + p;
    float xin[64];
#pragma unroll
    for (int c = 0; c < 64; c++) xin[c] = __bfloat162float(ip[(size_t)c * HWn]);
    bf16* op = out + ((size_t)b * co_total + co_start) * HWn + p;
    for (int o = 0; o < co_per; ++o) {
        const float* wr = ws + o * 64;
        float acc = 0.f;
#pragma unroll
        for (int c = 0; c < 64; c++) acc = fmaf(wr[c], xin[c], acc);
        op[(size_t)o * HWn] = __float2bfloat16(acc);
    }
}

// ---------- depthwise 3x3, SAME zero pad, 8 px/thread vectorized ----------
__global__ void dwconv3_v(const bf16* __restrict__ in, const float* __restrict__ w,
                          int CH, bf16* __restrict__ out) {
    int blk = blockIdx.x;              // img*32 + rowgroup
    int img = blk >> 5;                // b*CH + ch
    int rowg = (blk & 31) << 3;
    int ch = img % CH;
    int t = threadIdx.x;
    int r = rowg + (t >> 5);           // row 0..255
    int xs = (t & 31) << 3;            // col start, multiple of 8
    const bf16* base = in + (size_t)img * HWn;
    float wv[9];
#pragma unroll
    for (int i = 0; i < 9; i++) wv[i] = w[ch * 9 + i];
    float row[3][10];
#pragma unroll
    for (int dy = 0; dy < 3; dy++) {
        int ys = r + dy - 1;
#pragma unroll
        for (int i = 0; i < 10; i++) row[dy][i] = 0.f;
        if (ys >= 0 && ys < Hh) {
            const bf16* rp = base + (size_t)ys * Wd + xs;
            short8 v = *reinterpret_cast<const short8*>(rp);
#pragma unroll
            for (int i = 0; i < 8; i++) row[dy][i + 1] = b2f(v[i]);
            if (xs > 0)      row[dy][0] = b2f(*reinterpret_cast<const short*>(rp - 1));
            if (xs + 8 < Wd) row[dy][9] = b2f(*reinterpret_cast<const short*>(rp + 8));
        }
    }
    float acc[8];
#pragma unroll
    for (int j = 0; j < 8; j++) acc[j] = 0.f;
#pragma unroll
    for (int dy = 0; dy < 3; dy++)
#pragma unroll
        for (int dx = 0; dx < 3; dx++) {
            float wc = wv[dy * 3 + dx];
#pragma unroll
            for (int j = 0; j < 8; j++) acc[j] = fmaf(wc, row[dy][j + dx], acc[j]);
        }
    short8 o;
#pragma unroll
    for (int j = 0; j < 8; j++) o[j] = f2b(acc[j]);
    *reinterpret_cast<short8*>(out + (size_t)img * HWn + (size_t)r * Wd + xs) = o;
}

// ---------- attention dots + row norms fused ----------
// G[which][b][h][c][d] = sum_n A[c,n]*B[d,n];  NA/NB = row sumsq
__global__ void attn_dots_f(const bf16* __restrict__ txd, const bf16* __restrict__ tyd,
                            float* __restrict__ G, float* __restrict__ NA,
                            float* __restrict__ NB) {
    int which = blockIdx.z;
    int bh = blockIdx.y;
    int b = bh >> 3;
    int h = bh & 7;
    const bf16* Aq = (which == 0 ? tyd : txd) + ((size_t)b * 192 + h * 8) * HWn;
    const bf16* Bk = (which == 0 ? txd : tyd) + ((size_t)b * 192 + 64 + h * 8) * HWn;
    float acc[8][8], na[8], nb[8];
#pragma unroll
    for (int c = 0; c < 8; c++) {
        na[c] = 0.f; nb[c] = 0.f;
#pragma unroll
        for (int d = 0; d < 8; d++) acc[c][d] = 0.f;
    }
    int per = HWn / gridDim.x;
    int n0 = blockIdx.x * per;
    for (int n = n0 + threadIdx.x * 4; n < n0 + per; n += 1024) {
        float av[8][4], bv[8][4];
#pragma unroll
        for (int i = 0; i < 8; i++) {
            short4 a4 = *reinterpret_cast<const short4*>(Aq + (size_t)i * HWn + n);
            short4 b4 = *reinterpret_cast<const short4*>(Bk + (size_t)i * HWn + n);
            av[i][0] = b2f(a4.x); av[i][1] = b2f(a4.y); av[i][2] = b2f(a4.z); av[i][3] = b2f(a4.w);
            bv[i][0] = b2f(b4.x); bv[i][1] = b2f(b4.y); bv[i][2] = b2f(b4.z); bv[i][3] = b2f(b4.w);
        }
#pragma unroll
        for (int u = 0; u < 4; u++) {
#pragma unroll
            for (int c = 0; c < 8; c++) na[c] = fmaf(av[c][u], av[c][u], na[c]);
#pragma unroll
            for (int d = 0; d < 8; d++) nb[d] = fmaf(bv[d][u], bv[d][u], nb[d]);
#pragma unroll
            for (int c = 0; c < 8; c++)
#pragma unroll
                for (int d = 0; d < 8; d++) acc[c][d] = fmaf(av[c][u], bv[d][u], acc[c][d]);
        }
    }
    size_t gbase = (((size_t)which * Bb + b) * 8 + h);
    float* Gp = G + gbase * 64;
#pragma unroll
    for (int c = 0; c < 8; c++)
#pragma unroll
        for (int d = 0; d < 8; d++) {
            float s = acc[c][d];
#pragma unroll
            for (int m = 1; m < 64; m <<= 1) s += __shfl_xor(s, m);
            if ((threadIdx.x & 63) == 0) atomicAdd(&Gp[c * 8 + d], s);
        }
#pragma unroll
    for (int c = 0; c < 8; c++) {
        float s = na[c];
#pragma unroll
        for (int m = 1; m < 64; m <<= 1) s += __shfl_xor(s, m);
        if ((threadIdx.x & 63) == 0) atomicAdd(&NA[gbase * 8 + c], s);
        float s2 = nb[c];
#pragma unroll
        for (int m = 1; m < 64; m <<= 1) s2 += __shfl_xor(s2, m);
        if ((threadIdx.x & 63) == 0) atomicAdd(&NB[gbase * 8 + c], s2);
    }
}

// ---------- tiny softmax with l2norm scaling and temperature ----------
__global__ void attn_softmax(const float* __restrict__ G, const float* __restrict__ NA,
                             const float* __restrict__ NB, const float* __restrict__ temp,
                             float* __restrict__ A) {
    int t = threadIdx.x;               // (which,b,h,c)
    int h = (t >> 3) & 7;
    int c = t & 7;
    size_t rbase = t >> 3;             // (which*2+b)*8+h
    const float* Gp = G + rbase * 64 + c * 8;
    float an = fmaxf(sqrtf(NA[rbase * 8 + c]), 1e-12f);
    float tm = temp[h];
    float vals[8];
    float mx = -1e30f;
#pragma unroll
    for (int d = 0; d < 8; d++) {
        float bn = fmaxf(sqrtf(NB[rbase * 8 + d]), 1e-12f);
        float v = Gp[d] / (an * bn) * tm;
        vals[d] = v;
        mx = fmaxf(mx, v);
    }
    float se = 0.f;
#pragma unroll
    for (int d = 0; d < 8; d++) { vals[d] = expf(vals[d] - mx); se += vals[d]; }
    float inv = 1.f / se;
    float* Ap = A + rbase * 64 + c * 8;
#pragma unroll
    for (int d = 0; d < 8; d++) Ap[d] = vals[d] * inv;
}

// ---------- cross attention + residual + LN2 fused ----------
__global__ void cross_ln2(const float* __restrict__ x, const bf16* __restrict__ txd,
                          const bf16* __restrict__ tyd, const float* __restrict__ A,
                          const float* __restrict__ ln2w, const float* __restrict__ ln2b,
                          float* __restrict__ out, bf16* __restrict__ xn2) {
    int idx = blockIdx.x * 256 + threadIdx.x;
    int b = idx >> 16;
    int p = idx & 65535;
    __shared__ float a1[512], a2[512];     // [h][c][d] for this b
    for (int i = threadIdx.x; i < 512; i += 256) {
        a1[i] = A[(size_t)b * 512 + i];
        a2[i] = A[((size_t)2 + b) * 512 + i];
    }
    __syncthreads();
    float o[64];
    const float* xp = x + (size_t)b * 64 * HWn + p;
#pragma unroll
    for (int c = 0; c < 64; c++) o[c] = xp[(size_t)c * HWn];
    const bf16* vp  = txd + ((size_t)b * 192 + 128) * HWn + p;
    const bf16* vp1 = tyd + ((size_t)b * 192 + 128) * HWn + p;
#pragma unroll
    for (int h = 0; h < 8; h++) {
        float v[8], v1[8];
#pragma unroll
        for (int d = 0; d < 8; d++) {
            v[d]  = __bfloat162float(vp[((size_t)h * 8 + d) * HWn]);
            v1[d] = __bfloat162float(vp1[((size_t)h * 8 + d) * HWn]);
        }
#pragma unroll
        for (int c = 0; c < 8; c++) {
            float s = 0.f;
            const float* r1 = a1 + h * 64 + c * 8;
            const float* r2 = a2 + h * 64 + c * 8;
#pragma unroll
            for (int d = 0; d < 8; d++) s += r1[d] * v[d] + r2[d] * v1[d];
            o[h * 8 + c] += s;
        }
    }
    float* op = out + (size_t)b * 64 * HWn + p;
    float s = 0.f;
#pragma unroll
    for (int c = 0; c < 64; c++) { op[(size_t)c * HWn] = o[c]; s += o[c]; }
    float mu = s * (1.f / 64.f);
    float s2 = 0.f;
#pragma unroll
    for (int c = 0; c < 64; c++) { float d = o[c] - mu; s2 += d * d; }
    float inv = rsqrtf(s2 * (1.f / 64.f) + 1e-5f);
    bf16* np = xn2 + (size_t)b * 64 * HWn + p;
#pragma unroll
    for (int c = 0; c < 64; c++)
        np[(size_t)c * HWn] = __float2bfloat16((o[c] - mu) * inv * ln2w[c] + ln2b[c]);
}

// ---------- GDFN output: out += W_out @ (gelu(g1) * g2) ----------
__global__ void gdfn_out_k(const bf16* __restrict__ gd, const float* __restrict__ w,
                           float* __restrict__ out) {
    extern __shared__ float ws[];      // [64][170]
    for (int i = threadIdx.x; i < 64 * HIDc; i += 256) ws[i] = w[i];
    __syncthreads();
    int idx = blockIdx.x * 256 + threadIdx.x;
    int b = idx >> 16;
    int p = idx & 65535;
    const bf16* g1 = gd + (size_t)b * (2 * HIDc) * HWn + p;
    const bf16* g2 = g1 + (size_t)HIDc * HWn;
    float acc[64];
#pragma unroll
    for (int c = 0; c < 64; c++) acc[c] = 0.f;
    for (int hid = 0; hid < HIDc; ++hid) {
        float a = __bfloat162float(g1[(size_t)hid * HWn]);
        float g = __bfloat162float(g2[(size_t)hid * HWn]);
        float t = a * 0.5f * (1.f + erff(a * 0.70710678118654752f)) * g;
#pragma unroll
        for (int c = 0; c < 64; c++) acc[c] = fmaf(ws[c * HIDc + hid], t, acc[c]);
    }
    float* op = out + (size_t)b * 64 * HWn + p;
#pragma unroll
    for (int c = 0; c < 64; c++) op[(size_t)c * HWn] += acc[c];
}

extern "C" void kernel_launch(void* const* d_in, const int* in_sizes, int n_in,
                              void* d_out, int out_size, void* d_ws, size_t ws_size,
                              hipStream_t stream) {
    const float* x        = (const float*)d_in[0];
    const float* y        = (const float*)d_in[1];
    const float* ln11_w   = (const float*)d_in[2];
    const float* ln11_b   = (const float*)d_in[3];
    const float* ln12_w   = (const float*)d_in[4];
    const float* ln12_b   = (const float*)d_in[5];
    const float* ln2_w    = (const float*)d_in[6];
    const float* ln2_b    = (const float*)d_in[7];
    const float* qkv_w    = (const float*)d_in[8];
    const float* qkv_dw   = (const float*)d_in[9];
    const float* temp     = (const float*)d_in[10];
    const float* gdfn_in_w  = (const float*)d_in[11];
    const float* gdfn_dw    = (const float*)d_in[12];
    const float* gdfn_out_w = (const float*)d_in[13];
    float* out = (float*)d_out;

    char* ws = (char*)d_ws;
    float* G    = (float*)ws;          // 2048
    float* NA   = G + 2048;            // 256
    float* NB   = NA + 256;            // 256
    float* Amat = NB + 256;            // 2048
    size_t base = 18944;               // bytes, 256B aligned (4736 floats -> 18944 B)
    bf16* xn  = (bf16*)(ws + base);                       // 8,388,608 elems
    bf16* yn  = xn + (size_t)8388608;
    bf16* tx  = (bf16*)(ws + base + (size_t)33554432);    // 25,165,824 elems
    bf16* txd = tx + (size_t)25165824;
    bf16* tyd = txd + (size_t)25165824;
    bf16* g   = tx;                                       // reuse
    bf16* gd  = tx + (size_t)44564480;

    const int NPIXB = 512;             // B*HW/256

    zero_k<<<1, 256, 0, stream>>>(G, 2048 + 512);

    ln_ch_k<<<NPIXB, 256, 0, stream>>>(x, ln11_w, ln11_b, xn);
    ln_ch_k<<<NPIXB, 256, 0, stream>>>(y, ln12_w, ln12_b, yn);

    conv1x1_g<<<dim3(NPIXB, 3), 256, 64 * 64 * 4, stream>>>(xn, qkv_w, 64, 192, tx);
    dwconv3_v<<<Bb * 192 * 32, 256, 0, stream>>>(tx, qkv_dw, 192, txd);
    conv1x1_g<<<dim3(NPIXB, 3), 256, 64 * 64 * 4, stream>>>(yn, qkv_w, 64, 192, tx);
    dwconv3_v<<<Bb * 192 * 32, 256, 0, stream>>>(tx, qkv_dw, 192, tyd);

    attn_dots_f<<<dim3(16, 16, 2), 256, 0, stream>>>(txd, tyd, G, NA, NB);
    attn_softmax<<<1, 256, 0, stream>>>(G, NA, NB, temp, Amat);

    cross_ln2<<<NPIXB, 256, 0, stream>>>(x, txd, tyd, Amat, ln2_w, ln2_b, out, xn);

    conv1x1_g<<<dim3(NPIXB, 5), 256, 68 * 64 * 4, stream>>>(xn, gdfn_in_w, 68, 340, g);
    dwconv3_v<<<Bb * 340 * 32, 256, 0, stream>>>(g, gdfn_dw, 340, gd);
    gdfn_out_k<<<NPIXB, 256, 64 * HIDc * 4, stream>>>(gd, gdfn_out_w, out);
}

// Round 3
// 1124.557 us; speedup vs baseline: 1.5455x; 1.1500x over previous
//
#include <hip/hip_runtime.h>
#include <hip/hip_bf16.h>
#include <math.h>

#define HWn 65536
#define Hh 256
#define Wd 256
#define Bb 2
#define Cc 64
#define NHh 8
#define HIDc 170

typedef __hip_bfloat16 bf16;
typedef __attribute__((ext_vector_type(8))) short short8;

__device__ inline float b2f(short u) {
    unsigned int x = ((unsigned int)(unsigned short)u) << 16;
    return __uint_as_float(x);
}
__device__ inline short f2b(float f) {
    __hip_bfloat16 h = __float2bfloat16(f);
    return *reinterpret_cast<short*>(&h);
}

// ---------- zero small scratch ----------
__global__ void zero_k(float* p, int n) {
    for (int i = threadIdx.x; i < n; i += 256) p[i] = 0.f;
}

// ---------- per-pixel channel LayerNorm (64 ch), f32 in -> bf16 out ----------
__global__ __launch_bounds__(256, 4)
void ln_ch_k(const float* __restrict__ x, const float* __restrict__ w,
             const float* __restrict__ bia, bf16* __restrict__ out) {
    int idx = blockIdx.x * 256 + threadIdx.x;
    int b = idx >> 16;
    int p = idx & 65535;
    const float* xp = x + (size_t)b * Cc * HWn + p;
    float f[64];
    float s = 0.f;
#pragma unroll
    for (int c = 0; c < 64; c++) { f[c] = xp[(size_t)c * HWn]; s += f[c]; }
    float mu = s * (1.f / 64.f);
    float s2 = 0.f;
#pragma unroll
    for (int c = 0; c < 64; c++) { float d = f[c] - mu; s2 += d * d; }
    float inv = rsqrtf(s2 * (1.f / 64.f) + 1e-5f);
    bf16* op = out + (size_t)b * Cc * HWn + p;
#pragma unroll
    for (int c = 0; c < 64; c++)
        op[(size_t)c * HWn] = __float2bfloat16((f[c] - mu) * inv * w[c] + bia[c]);
}

// ---------- 1x1 conv, 64 in -> co_per out per y-group (weights in LDS) ----------
__global__ __launch_bounds__(256, 4)
void conv1x1_g(const bf16* __restrict__ in, const float* __restrict__ w,
               int co_per, int co_total, bf16* __restrict__ out) {
    extern __shared__ float ws[];
    int co_start = blockIdx.y * co_per;
    for (int i = threadIdx.x; i < co_per * 64; i += 256) ws[i] = w[co_start * 64 + i];
    __syncthreads();
    int idx = blockIdx.x * 256 + threadIdx.x;
    int b = idx >> 16;
    int p = idx & 65535;
    const bf16* ip = in + (size_t)b * 64 * HWn + p;
    float xin[64];
#pragma unroll
    for (int c = 0; c < 64; c++) xin[c] = __bfloat162float(ip[(size_t)c * HWn]);
    bf16* op = out + ((size_t)b * co_total + co_start) * HWn + p;
    for (int o = 0; o < co_per; ++o) {
        const float* wr = ws + o * 64;
        float acc = 0.f;
#pragma unroll
        for (int c = 0; c < 64; c++) acc = fmaf(wr[c], xin[c], acc);
        op[(size_t)o * HWn] = __float2bfloat16(acc);
    }
}

// ---------- depthwise 3x3, SAME zero pad, 8 px/thread vectorized ----------
__global__ __launch_bounds__(256, 4)
void dwconv3_v(const bf16* __restrict__ in, const float* __restrict__ w,
               int CH, bf16* __restrict__ out) {
    int blk = blockIdx.x;              // img*32 + rowgroup
    int img = blk >> 5;                // b*CH + ch
    int rowg = (blk & 31) << 3;
    int ch = img % CH;
    int t = threadIdx.x;
    int r = rowg + (t >> 5);           // row 0..255
    int xs = (t & 31) << 3;            // col start, multiple of 8
    const bf16* base = in + (size_t)img * HWn;
    float wv[9];
#pragma unroll
    for (int i = 0; i < 9; i++) wv[i] = w[ch * 9 + i];
    float row[3][10];
#pragma unroll
    for (int dy = 0; dy < 3; dy++) {
        int ys = r + dy - 1;
#pragma unroll
        for (int i = 0; i < 10; i++) row[dy][i] = 0.f;
        if (ys >= 0 && ys < Hh) {
            const bf16* rp = base + (size_t)ys * Wd + xs;
            short8 v = *reinterpret_cast<const short8*>(rp);
#pragma unroll
            for (int i = 0; i < 8; i++) row[dy][i + 1] = b2f(v[i]);
            if (xs > 0)      row[dy][0] = b2f(*reinterpret_cast<const short*>(rp - 1));
            if (xs + 8 < Wd) row[dy][9] = b2f(*reinterpret_cast<const short*>(rp + 8));
        }
    }
    float acc[8];
#pragma unroll
    for (int j = 0; j < 8; j++) acc[j] = 0.f;
#pragma unroll
    for (int dy = 0; dy < 3; dy++)
#pragma unroll
        for (int dx = 0; dx < 3; dx++) {
            float wc = wv[dy * 3 + dx];
#pragma unroll
            for (int j = 0; j < 8; j++) acc[j] = fmaf(wc, row[dy][j + dx], acc[j]);
        }
    short8 o;
#pragma unroll
    for (int j = 0; j < 8; j++) o[j] = f2b(acc[j]);
    *reinterpret_cast<short8*>(out + (size_t)img * HWn + (size_t)r * Wd + xs) = o;
}

// ---------- attention dots + row norms fused ----------
__global__ __launch_bounds__(256, 2)
void attn_dots_f(const bf16* __restrict__ txd, const bf16* __restrict__ tyd,
                 float* __restrict__ G, float* __restrict__ NA,
                 float* __restrict__ NB) {
    int which = blockIdx.z;
    int bh = blockIdx.y;
    int b = bh >> 3;
    int h = bh & 7;
    const bf16* Aq = (which == 0 ? tyd : txd) + ((size_t)b * 192 + h * 8) * HWn;
    const bf16* Bk = (which == 0 ? txd : tyd) + ((size_t)b * 192 + 64 + h * 8) * HWn;
    float acc[8][8], na[8], nb[8];
#pragma unroll
    for (int c = 0; c < 8; c++) {
        na[c] = 0.f; nb[c] = 0.f;
#pragma unroll
        for (int d = 0; d < 8; d++) acc[c][d] = 0.f;
    }
    int per = HWn / gridDim.x;
    int n0 = blockIdx.x * per;
    for (int n = n0 + threadIdx.x * 4; n < n0 + per; n += 1024) {
        float av[8][4], bv[8][4];
#pragma unroll
        for (int i = 0; i < 8; i++) {
            short4 a4 = *reinterpret_cast<const short4*>(Aq + (size_t)i * HWn + n);
            short4 b4 = *reinterpret_cast<const short4*>(Bk + (size_t)i * HWn + n);
            av[i][0] = b2f(a4.x); av[i][1] = b2f(a4.y); av[i][2] = b2f(a4.z); av[i][3] = b2f(a4.w);
            bv[i][0] = b2f(b4.x); bv[i][1] = b2f(b4.y); bv[i][2] = b2f(b4.z); bv[i][3] = b2f(b4.w);
        }
#pragma unroll
        for (int u = 0; u < 4; u++) {
#pragma unroll
            for (int c = 0; c < 8; c++) na[c] = fmaf(av[c][u], av[c][u], na[c]);
#pragma unroll
            for (int d = 0; d < 8; d++) nb[d] = fmaf(bv[d][u], bv[d][u], nb[d]);
#pragma unroll
            for (int c = 0; c < 8; c++)
#pragma unroll
                for (int d = 0; d < 8; d++) acc[c][d] = fmaf(av[c][u], bv[d][u], acc[c][d]);
        }
    }
    size_t gbase = (((size_t)which * Bb + b) * 8 + h);
    float* Gp = G + gbase * 64;
#pragma unroll
    for (int c = 0; c < 8; c++)
#pragma unroll
        for (int d = 0; d < 8; d++) {
            float s = acc[c][d];
#pragma unroll
            for (int m = 1; m < 64; m <<= 1) s += __shfl_xor(s, m);
            if ((threadIdx.x & 63) == 0) atomicAdd(&Gp[c * 8 + d], s);
        }
#pragma unroll
    for (int c = 0; c < 8; c++) {
        float s = na[c];
#pragma unroll
        for (int m = 1; m < 64; m <<= 1) s += __shfl_xor(s, m);
        if ((threadIdx.x & 63) == 0) atomicAdd(&NA[gbase * 8 + c], s);
        float s2 = nb[c];
#pragma unroll
        for (int m = 1; m < 64; m <<= 1) s2 += __shfl_xor(s2, m);
        if ((threadIdx.x & 63) == 0) atomicAdd(&NB[gbase * 8 + c], s2);
    }
}

// ---------- tiny softmax with l2norm scaling and temperature ----------
__global__ void attn_softmax(const float* __restrict__ G, const float* __restrict__ NA,
                             const float* __restrict__ NB, const float* __restrict__ temp,
                             float* __restrict__ A) {
    int t = threadIdx.x;               // (which,b,h,c)
    int h = (t >> 3) & 7;
    int c = t & 7;
    size_t rbase = t >> 3;             // (which*2+b)*8+h
    const float* Gp = G + rbase * 64 + c * 8;
    float an = fmaxf(sqrtf(NA[rbase * 8 + c]), 1e-12f);
    float tm = temp[h];
    float vals[8];
    float mx = -1e30f;
#pragma unroll
    for (int d = 0; d < 8; d++) {
        float bn = fmaxf(sqrtf(NB[rbase * 8 + d]), 1e-12f);
        float v = Gp[d] / (an * bn) * tm;
        vals[d] = v;
        mx = fmaxf(mx, v);
    }
    float se = 0.f;
#pragma unroll
    for (int d = 0; d < 8; d++) { vals[d] = expf(vals[d] - mx); se += vals[d]; }
    float inv = 1.f / se;
    float* Ap = A + rbase * 64 + c * 8;
#pragma unroll
    for (int d = 0; d < 8; d++) Ap[d] = vals[d] * inv;
}

// ---------- cross attention + residual + LN2 fused ----------
__global__ __launch_bounds__(256, 4)
void cross_ln2(const float* __restrict__ x, const bf16* __restrict__ txd,
               const bf16* __restrict__ tyd, const float* __restrict__ A,
               const float* __restrict__ ln2w, const float* __restrict__ ln2b,
               float* __restrict__ out, bf16* __restrict__ xn2) {
    int idx = blockIdx.x * 256 + threadIdx.x;
    int b = idx >> 16;
    int p = idx & 65535;
    __shared__ float a1[512], a2[512];     // [h][c][d] for this b
    for (int i = threadIdx.x; i < 512; i += 256) {
        a1[i] = A[(size_t)b * 512 + i];
        a2[i] = A[((size_t)2 + b) * 512 + i];
    }
    __syncthreads();
    float o[64];
    const float* xp = x + (size_t)b * 64 * HWn + p;
#pragma unroll
    for (int c = 0; c < 64; c++) o[c] = xp[(size_t)c * HWn];
    const bf16* vp  = txd + ((size_t)b * 192 + 128) * HWn + p;
    const bf16* vp1 = tyd + ((size_t)b * 192 + 128) * HWn + p;
#pragma unroll
    for (int h = 0; h < 8; h++) {
        float v[8], v1[8];
#pragma unroll
        for (int d = 0; d < 8; d++) {
            v[d]  = __bfloat162float(vp[((size_t)h * 8 + d) * HWn]);
            v1[d] = __bfloat162float(vp1[((size_t)h * 8 + d) * HWn]);
        }
#pragma unroll
        for (int c = 0; c < 8; c++) {
            float s = 0.f;
            const float* r1 = a1 + h * 64 + c * 8;
            const float* r2 = a2 + h * 64 + c * 8;
#pragma unroll
            for (int d = 0; d < 8; d++) s += r1[d] * v[d] + r2[d] * v1[d];
            o[h * 8 + c] += s;
        }
    }
    float* op = out + (size_t)b * 64 * HWn + p;
    float s = 0.f;
#pragma unroll
    for (int c = 0; c < 64; c++) { op[(size_t)c * HWn] = o[c]; s += o[c]; }
    float mu = s * (1.f / 64.f);
    float s2 = 0.f;
#pragma unroll
    for (int c = 0; c < 64; c++) { float d = o[c] - mu; s2 += d * d; }
    float inv = rsqrtf(s2 * (1.f / 64.f) + 1e-5f);
    bf16* np = xn2 + (size_t)b * 64 * HWn + p;
#pragma unroll
    for (int c = 0; c < 64; c++)
        np[(size_t)c * HWn] = __float2bfloat16((o[c] - mu) * inv * ln2w[c] + ln2b[c]);
}

// ---------- GDFN output: out += W_out @ (gelu(g1) * g2) ----------
__global__ __launch_bounds__(256, 4)
void gdfn_out_k(const bf16* __restrict__ gd, const float* __restrict__ w,
                float* __restrict__ out) {
    extern __shared__ float ws[];      // [64][170]
    for (int i = threadIdx.x; i < 64 * HIDc; i += 256) ws[i] = w[i];
    __syncthreads();
    int idx = blockIdx.x * 256 + threadIdx.x;
    int b = idx >> 16;
    int p = idx & 65535;
    const bf16* g1 = gd + (size_t)b * (2 * HIDc) * HWn + p;
    const bf16* g2 = g1 + (size_t)HIDc * HWn;
    float acc[64];
#pragma unroll
    for (int c = 0; c < 64; c++) acc[c] = 0.f;
    for (int hid = 0; hid < HIDc; ++hid) {
        float a = __bfloat162float(g1[(size_t)hid * HWn]);
        float g = __bfloat162float(g2[(size_t)hid * HWn]);
        float t = a * 0.5f * (1.f + erff(a * 0.70710678118654752f)) * g;
#pragma unroll
        for (int c = 0; c < 64; c++) acc[c] = fmaf(ws[c * HIDc + hid], t, acc[c]);
    }
    float* op = out + (size_t)b * 64 * HWn + p;
#pragma unroll
    for (int c = 0; c < 64; c++) op[(size_t)c * HWn] += acc[c];
}

extern "C" void kernel_launch(void* const* d_in, const int* in_sizes, int n_in,
                              void* d_out, int out_size, void* d_ws, size_t ws_size,
                              hipStream_t stream) {
    const float* x        = (const float*)d_in[0];
    const float* y        = (const float*)d_in[1];
    const float* ln11_w   = (const float*)d_in[2];
    const float* ln11_b   = (const float*)d_in[3];
    const float* ln12_w   = (const float*)d_in[4];
    const float* ln12_b   = (const float*)d_in[5];
    const float* ln2_w    = (const float*)d_in[6];
    const float* ln2_b    = (const float*)d_in[7];
    const float* qkv_w    = (const float*)d_in[8];
    const float* qkv_dw   = (const float*)d_in[9];
    const float* temp     = (const float*)d_in[10];
    const float* gdfn_in_w  = (const float*)d_in[11];
    const float* gdfn_dw    = (const float*)d_in[12];
    const float* gdfn_out_w = (const float*)d_in[13];
    float* out = (float*)d_out;

    char* ws = (char*)d_ws;
    float* G    = (float*)ws;          // 2048
    float* NA   = G + 2048;            // 256
    float* NB   = NA + 256;            // 256
    float* Amat = NB + 256;            // 2048
    size_t base = 18944;               // bytes, 256B aligned
    bf16* xn  = (bf16*)(ws + base);                       // 8,388,608 elems
    bf16* yn  = xn + (size_t)8388608;
    bf16* tx  = (bf16*)(ws + base + (size_t)33554432);    // 25,165,824 elems
    bf16* txd = tx + (size_t)25165824;
    bf16* tyd = txd + (size_t)25165824;
    bf16* g   = tx;                                       // reuse
    bf16* gd  = tx + (size_t)44564480;

    const int NPIXB = 512;             // B*HW/256

    zero_k<<<1, 256, 0, stream>>>(G, 2048 + 512);

    ln_ch_k<<<NPIXB, 256, 0, stream>>>(x, ln11_w, ln11_b, xn);
    ln_ch_k<<<NPIXB, 256, 0, stream>>>(y, ln12_w, ln12_b, yn);

    conv1x1_g<<<dim3(NPIXB, 3), 256, 64 * 64 * 4, stream>>>(xn, qkv_w, 64, 192, tx);
    dwconv3_v<<<Bb * 192 * 32, 256, 0, stream>>>(tx, qkv_dw, 192, txd);
    conv1x1_g<<<dim3(NPIXB, 3), 256, 64 * 64 * 4, stream>>>(yn, qkv_w, 64, 192, tx);
    dwconv3_v<<<Bb * 192 * 32, 256, 0, stream>>>(tx, qkv_dw, 192, tyd);

    attn_dots_f<<<dim3(16, 16, 2), 256, 0, stream>>>(txd, tyd, G, NA, NB);
    attn_softmax<<<1, 256, 0, stream>>>(G, NA, NB, temp, Amat);

    cross_ln2<<<NPIXB, 256, 0, stream>>>(x, txd, tyd, Amat, ln2_w, ln2_b, out, xn);

    conv1x1_g<<<dim3(NPIXB, 5), 256, 68 * 64 * 4, stream>>>(xn, gdfn_in_w, 68, 340, g);
    dwconv3_v<<<Bb * 340 * 32, 256, 0, stream>>>(g, gdfn_dw, 340, gd);
    gdfn_out_k<<<NPIXB, 256, 64 * HIDc * 4, stream>>>(gd, gdfn_out_w, out);
}

// Round 4
// 1097.133 us; speedup vs baseline: 1.5842x; 1.0250x over previous
//
#include <hip/hip_runtime.h>
#include <hip/hip_bf16.h>
#include <math.h>

#define HWn 65536
#define Hh 256
#define Wd 256
#define Bb 2
#define Cc 64
#define NHh 8
#define HIDc 170

typedef __hip_bfloat16 bf16;
typedef __attribute__((ext_vector_type(8))) short short8;
typedef __attribute__((ext_vector_type(4))) short s16x4;
typedef __attribute__((ext_vector_type(4))) float f32x4;

__device__ inline float b2f(short u) {
    unsigned int x = ((unsigned int)(unsigned short)u) << 16;
    return __uint_as_float(x);
}
__device__ inline short f2b(float f) {
    __hip_bfloat16 h = __float2bfloat16(f);
    return *reinterpret_cast<short*>(&h);
}

// ---------- zero small scratch ----------
__global__ void zero_k(float* p, int n) {
    for (int i = threadIdx.x; i < n; i += 256) p[i] = 0.f;
}

// ---------- LayerNorm over 64 ch: f32 [b][c][hw] in -> bf16 [px][64] out ----------
__global__ __launch_bounds__(256, 2)
void ln_px(const float* __restrict__ x, const float* __restrict__ w,
           const float* __restrict__ bia, bf16* __restrict__ out) {
    int idx = blockIdx.x * 256 + threadIdx.x;
    int b = idx >> 16, p = idx & 65535;
    const float* xp = x + (size_t)b * 64 * HWn + p;
    float f[64];
    float s = 0.f;
#pragma unroll
    for (int c = 0; c < 64; c++) { f[c] = xp[(size_t)c * HWn]; s += f[c]; }
    float mu = s * (1.f / 64.f);
    float s2 = 0.f;
#pragma unroll
    for (int c = 0; c < 64; c++) { float d = f[c] - mu; s2 += d * d; }
    float inv = rsqrtf(s2 * (1.f / 64.f) + 1e-5f);
    bf16* op = out + (size_t)idx * 64;
#pragma unroll
    for (int c8 = 0; c8 < 64; c8 += 8) {
        short8 o;
#pragma unroll
        for (int e = 0; e < 8; e++)
            o[e] = f2b((f[c8 + e] - mu) * inv * w[c8 + e] + bia[c8 + e]);
        *reinterpret_cast<short8*>(op + c8) = o;
    }
}

// ---------- 1x1 conv via MFMA: in [px][64] bf16, W [rows][64] f32 -> out [px][co_stride] ----------
// Block: 64 px x 64 co (4 waves, one 16-co strip each). remap: GDFN g1|pad|g2 row mapping.
__global__ __launch_bounds__(256)
void conv1x1_mfma(const bf16* __restrict__ in, const float* __restrict__ w,
                  int co_stride, int remap, bf16* __restrict__ out) {
    int lane = threadIdx.x & 63;
    int wid = threadIdx.x >> 6;
    int strip = blockIdx.y * 4 + wid;
    if (strip * 16 >= co_stride) return;
    int r16 = lane & 15, grp = lane >> 4;
    int co = strip * 16 + r16;
    int row = remap ? (co < 170 ? co : (co >= 176 && co < 346 ? co - 6 : -1)) : co;
    short8 a0, a1;
    if (row >= 0) {
        const float* wr = w + (size_t)row * 64 + grp * 8;
#pragma unroll
        for (int e = 0; e < 8; e++) { a0[e] = f2b(wr[e]); a1[e] = f2b(wr[32 + e]); }
    } else {
#pragma unroll
        for (int e = 0; e < 8; e++) { a0[e] = 0; a1[e] = 0; }
    }
    size_t px0 = (size_t)blockIdx.x * 64;
    const bf16* bp = in + (px0 + r16) * 64 + grp * 8;
#pragma unroll
    for (int s = 0; s < 4; s++) {
        short8 b0 = *reinterpret_cast<const short8*>(bp + s * 1024);
        short8 b1 = *reinterpret_cast<const short8*>(bp + s * 1024 + 32);
        f32x4 acc = {0.f, 0.f, 0.f, 0.f};
        acc = __builtin_amdgcn_mfma_f32_16x16x32_bf16(a0, b0, acc, 0, 0, 0);
        acc = __builtin_amdgcn_mfma_f32_16x16x32_bf16(a1, b1, acc, 0, 0, 0);
        size_t px = px0 + s * 16 + r16;
        s16x4 o;
#pragma unroll
        for (int j = 0; j < 4; j++) o[j] = f2b(acc[j]);
        *reinterpret_cast<s16x4*>(out + px * co_stride + strip * 16 + grp * 4) = o;
    }
}

// ---------- depthwise 3x3 in pixel-major layout: one px/thread, ch in short8 chunks ----------
__global__ __launch_bounds__(256)
void dwconv3_px(const bf16* __restrict__ in, const float* __restrict__ w,
                int CH, int remap, bf16* __restrict__ out) {
    __shared__ float wl[352 * 9];
    int tid = threadIdx.x;
    for (int i = tid; i < CH * 9; i += 256) {
        int c = i / 9, t9 = i - c * 9;
        int row = remap ? (c < 170 ? c : (c >= 176 && c < 346 ? c - 6 : -1)) : c;
        wl[i] = (row >= 0) ? w[row * 9 + t9] : 0.f;
    }
    __syncthreads();
    int idx = blockIdx.x * 256 + tid;
    int p = idx & 65535;
    int yy = p >> 8, xx = p & 255;
    for (int c8 = 0; c8 < CH; c8 += 8) {
        float acc[8];
#pragma unroll
        for (int e = 0; e < 8; e++) acc[e] = 0.f;
#pragma unroll
        for (int dy = -1; dy <= 1; dy++) {
            int ys = yy + dy;
            if (ys < 0 || ys >= Hh) continue;
#pragma unroll
            for (int dx = -1; dx <= 1; dx++) {
                int xs = xx + dx;
                if (xs < 0 || xs >= Wd) continue;
                short8 v = *reinterpret_cast<const short8*>(
                    in + ((size_t)idx + dy * 256 + dx) * CH + c8);
#pragma unroll
                for (int e = 0; e < 8; e++)
                    acc[e] = fmaf(wl[(c8 + e) * 9 + (dy + 1) * 3 + dx + 1], b2f(v[e]), acc[e]);
            }
        }
        short8 o;
#pragma unroll
        for (int e = 0; e < 8; e++) o[e] = f2b(acc[e]);
        *reinterpret_cast<short8*>(out + (size_t)idx * CH + c8) = o;
    }
}

// ---------- attention dots + row norms (pixel-major) ----------
__global__ __launch_bounds__(256, 2)
void attn_dots_px(const bf16* __restrict__ txd, const bf16* __restrict__ tyd,
                  float* __restrict__ G, float* __restrict__ NA,
                  float* __restrict__ NB) {
    int which = blockIdx.z;
    int bh = blockIdx.y;
    int b = bh >> 3, h = bh & 7;
    const bf16* Aq = (which == 0 ? tyd : txd) + (size_t)b * 65536 * 192 + h * 8;
    const bf16* Bk = (which == 0 ? txd : tyd) + (size_t)b * 65536 * 192 + 64 + h * 8;
    float acc[8][8], na[8], nb[8];
#pragma unroll
    for (int c = 0; c < 8; c++) {
        na[c] = 0.f; nb[c] = 0.f;
#pragma unroll
        for (int d = 0; d < 8; d++) acc[c][d] = 0.f;
    }
    int per = 65536 / gridDim.x;
    int n0 = blockIdx.x * per;
    for (int n = n0 + threadIdx.x; n < n0 + per; n += 256) {
        short8 q8 = *reinterpret_cast<const short8*>(Aq + (size_t)n * 192);
        short8 k8 = *reinterpret_cast<const short8*>(Bk + (size_t)n * 192);
        float av[8], bv[8];
#pragma unroll
        for (int i = 0; i < 8; i++) { av[i] = b2f(q8[i]); bv[i] = b2f(k8[i]); }
#pragma unroll
        for (int c = 0; c < 8; c++) na[c] = fmaf(av[c], av[c], na[c]);
#pragma unroll
        for (int d = 0; d < 8; d++) nb[d] = fmaf(bv[d], bv[d], nb[d]);
#pragma unroll
        for (int c = 0; c < 8; c++)
#pragma unroll
            for (int d = 0; d < 8; d++) acc[c][d] = fmaf(av[c], bv[d], acc[c][d]);
    }
    size_t gbase = (((size_t)which * Bb + b) * 8 + h);
    float* Gp = G + gbase * 64;
#pragma unroll
    for (int c = 0; c < 8; c++)
#pragma unroll
        for (int d = 0; d < 8; d++) {
            float s = acc[c][d];
#pragma unroll
            for (int m = 1; m < 64; m <<= 1) s += __shfl_xor(s, m);
            if ((threadIdx.x & 63) == 0) atomicAdd(&Gp[c * 8 + d], s);
        }
#pragma unroll
    for (int c = 0; c < 8; c++) {
        float s = na[c];
#pragma unroll
        for (int m = 1; m < 64; m <<= 1) s += __shfl_xor(s, m);
        if ((threadIdx.x & 63) == 0) atomicAdd(&NA[gbase * 8 + c], s);
        float s2 = nb[c];
#pragma unroll
        for (int m = 1; m < 64; m <<= 1) s2 += __shfl_xor(s2, m);
        if ((threadIdx.x & 63) == 0) atomicAdd(&NB[gbase * 8 + c], s2);
    }
}

// ---------- tiny softmax with l2norm scaling and temperature ----------
__global__ void attn_softmax(const float* __restrict__ G, const float* __restrict__ NA,
                             const float* __restrict__ NB, const float* __restrict__ temp,
                             float* __restrict__ A) {
    int t = threadIdx.x;
    int h = (t >> 3) & 7;
    int c = t & 7;
    size_t rbase = t >> 3;
    const float* Gp = G + rbase * 64 + c * 8;
    float an = fmaxf(sqrtf(NA[rbase * 8 + c]), 1e-12f);
    float tm = temp[h];
    float vals[8];
    float mx = -1e30f;
#pragma unroll
    for (int d = 0; d < 8; d++) {
        float bn = fmaxf(sqrtf(NB[rbase * 8 + d]), 1e-12f);
        float v = Gp[d] / (an * bn) * tm;
        vals[d] = v;
        mx = fmaxf(mx, v);
    }
    float se = 0.f;
#pragma unroll
    for (int d = 0; d < 8; d++) { vals[d] = expf(vals[d] - mx); se += vals[d]; }
    float inv = 1.f / se;
    float* Ap = A + rbase * 64 + c * 8;
#pragma unroll
    for (int d = 0; d < 8; d++) Ap[d] = vals[d] * inv;
}

// ---------- cross attention + residual + LN2 (pixel-major v) ----------
__global__ __launch_bounds__(256, 2)
void cross_ln2_px(const float* __restrict__ x, const bf16* __restrict__ txd,
                  const bf16* __restrict__ tyd, const float* __restrict__ A,
                  const float* __restrict__ ln2w, const float* __restrict__ ln2b,
                  float* __restrict__ out, bf16* __restrict__ xn2) {
    int idx = blockIdx.x * 256 + threadIdx.x;
    int b = idx >> 16, p = idx & 65535;
    __shared__ float a1[512], a2[512];
    for (int i = threadIdx.x; i < 512; i += 256) {
        a1[i] = A[(size_t)b * 512 + i];
        a2[i] = A[((size_t)2 + b) * 512 + i];
    }
    __syncthreads();
    float o[64];
    const float* xp = x + (size_t)b * 64 * HWn + p;
#pragma unroll
    for (int c = 0; c < 64; c++) o[c] = xp[(size_t)c * HWn];
    const bf16* vp = txd + (size_t)idx * 192 + 128;
    const bf16* vp1 = tyd + (size_t)idx * 192 + 128;
#pragma unroll
    for (int h = 0; h < 8; h++) {
        short8 v8 = *reinterpret_cast<const short8*>(vp + h * 8);
        short8 w8 = *reinterpret_cast<const short8*>(vp1 + h * 8);
        float v[8], v1[8];
#pragma unroll
        for (int d = 0; d < 8; d++) { v[d] = b2f(v8[d]); v1[d] = b2f(w8[d]); }
#pragma unroll
        for (int ci = 0; ci < 8; ci++) {
            float s = 0.f;
            const float* r1 = a1 + h * 64 + ci * 8;
            const float* r2 = a2 + h * 64 + ci * 8;
#pragma unroll
            for (int d = 0; d < 8; d++) s += r1[d] * v[d] + r2[d] * v1[d];
            o[h * 8 + ci] += s;
        }
    }
    float* op = out + (size_t)b * 64 * HWn + p;
    float s = 0.f;
#pragma unroll
    for (int c = 0; c < 64; c++) { op[(size_t)c * HWn] = o[c]; s += o[c]; }
    float mu = s * (1.f / 64.f);
    float s2 = 0.f;
#pragma unroll
    for (int c = 0; c < 64; c++) { float d = o[c] - mu; s2 += d * d; }
    float inv = rsqrtf(s2 * (1.f / 64.f) + 1e-5f);
    bf16* np = xn2 + (size_t)idx * 64;
#pragma unroll
    for (int c8 = 0; c8 < 64; c8 += 8) {
        short8 o8;
#pragma unroll
        for (int e = 0; e < 8; e++)
            o8[e] = f2b((o[c8 + e] - mu) * inv * ln2w[c8 + e] + ln2b[c8 + e]);
        *reinterpret_cast<short8*>(np + c8) = o8;
    }
}

// ---------- GDFN out: stage t=gelu(g1)*g2 in LDS, MFMA 170->64, accumulate into out ----------
__global__ __launch_bounds__(256)
void gdfn_out_mfma(const bf16* __restrict__ gd, const float* __restrict__ wout,
                   float* __restrict__ out) {
    __shared__ short tl[64 * 176 + 32];
    int tid = threadIdx.x;
    size_t px0 = (size_t)blockIdx.x * 64;
    int pxl = tid >> 2;
    const bf16* gp = gd + (px0 + pxl) * 352;
    for (int ch8 = (tid & 3); ch8 < 22; ch8 += 4) {
        int hid = ch8 * 8;
        short8 g1 = *reinterpret_cast<const short8*>(gp + hid);
        short8 g2 = *reinterpret_cast<const short8*>(gp + 176 + hid);
        short8 t;
#pragma unroll
        for (int e = 0; e < 8; e++) {
            float a = b2f(g1[e]);
            float gg = b2f(g2[e]);
            t[e] = f2b(a * 0.5f * (1.f + erff(a * 0.70710678118654752f)) * gg);
        }
        *reinterpret_cast<short8*>(&tl[pxl * 176 + hid]) = t;
    }
    if (tid < 32) tl[64 * 176 + tid] = 0;
    __syncthreads();
    int lane = tid & 63, wid = tid >> 6;
    int r16 = lane & 15, grp = lane >> 4;
    int co = wid * 16 + r16;
    short8 af[6];
#pragma unroll
    for (int kc = 0; kc < 6; kc++) {
#pragma unroll
        for (int e = 0; e < 8; e++) {
            int k = kc * 32 + grp * 8 + e;
            af[kc][e] = (k < 170) ? f2b(wout[(size_t)co * 170 + k]) : (short)0;
        }
    }
#pragma unroll
    for (int s = 0; s < 4; s++) {
        f32x4 acc = {0.f, 0.f, 0.f, 0.f};
        const short* tp = &tl[(s * 16 + r16) * 176 + grp * 8];
#pragma unroll
        for (int kc = 0; kc < 6; kc++) {
            short8 bv = *reinterpret_cast<const short8*>(tp + kc * 32);
            acc = __builtin_amdgcn_mfma_f32_16x16x32_bf16(af[kc], bv, acc, 0, 0, 0);
        }
        size_t px = px0 + s * 16 + r16;
        int b = (int)(px >> 16);
        int p = (int)(px & 65535);
        float* op = out + (size_t)b * 64 * HWn + (size_t)(wid * 16 + grp * 4) * HWn + p;
#pragma unroll
        for (int j = 0; j < 4; j++) op[(size_t)j * HWn] += acc[j];
    }
}

extern "C" void kernel_launch(void* const* d_in, const int* in_sizes, int n_in,
                              void* d_out, int out_size, void* d_ws, size_t ws_size,
                              hipStream_t stream) {
    const float* x = (const float*)d_in[0];
    const float* y = (const float*)d_in[1];
    const float* ln11_w = (const float*)d_in[2];
    const float* ln11_b = (const float*)d_in[3];
    const float* ln12_w = (const float*)d_in[4];
    const float* ln12_b = (const float*)d_in[5];
    const float* ln2_w = (const float*)d_in[6];
    const float* ln2_b = (const float*)d_in[7];
    const float* qkv_w = (const float*)d_in[8];
    const float* qkv_dw = (const float*)d_in[9];
    const float* temp = (const float*)d_in[10];
    const float* gdfn_in_w = (const float*)d_in[11];
    const float* gdfn_dw = (const float*)d_in[12];
    const float* gdfn_out_w = (const float*)d_in[13];
    float* out = (float*)d_out;

    char* wsb = (char*)d_ws;
    float* G = (float*)wsb;            // 2048
    float* NA = G + 2048;              // 256
    float* NB = NA + 256;              // 256
    float* Amat = NB + 256;            // 2048
    bf16* hp = (bf16*)(wsb + 18944);
    bf16* xn  = hp;                    // [131072][64]
    bf16* yn  = hp + (size_t)8388608;  // [131072][64]
    bf16* tx  = hp + (size_t)16777216; // [131072][192]
    bf16* txd = hp + (size_t)41943040; // [131072][192]
    bf16* tyd = hp + (size_t)67108864; // [131072][192]
    bf16* g   = hp + (size_t)8388608;  // [131072][352] overlays yn/tx/txd (dead by then)
    bf16* gd  = hp + (size_t)54525952; // [131072][352] overlays txd/tyd (dead by then)

    zero_k<<<1, 256, 0, stream>>>(G, 2048 + 512);

    ln_px<<<512, 256, 0, stream>>>(x, ln11_w, ln11_b, xn);
    ln_px<<<512, 256, 0, stream>>>(y, ln12_w, ln12_b, yn);

    conv1x1_mfma<<<dim3(2048, 3), 256, 0, stream>>>(xn, qkv_w, 192, 0, tx);
    dwconv3_px<<<512, 256, 0, stream>>>(tx, qkv_dw, 192, 0, txd);
    conv1x1_mfma<<<dim3(2048, 3), 256, 0, stream>>>(yn, qkv_w, 192, 0, tx);
    dwconv3_px<<<512, 256, 0, stream>>>(tx, qkv_dw, 192, 0, tyd);

    attn_dots_px<<<dim3(16, 16, 2), 256, 0, stream>>>(txd, tyd, G, NA, NB);
    attn_softmax<<<1, 256, 0, stream>>>(G, NA, NB, temp, Amat);

    cross_ln2_px<<<512, 256, 0, stream>>>(x, txd, tyd, Amat, ln2_w, ln2_b, out, xn);

    conv1x1_mfma<<<dim3(2048, 6), 256, 0, stream>>>(xn, gdfn_in_w, 352, 1, g);
    dwconv3_px<<<512, 256, 0, stream>>>(g, gdfn_dw, 352, 1, gd);
    gdfn_out_mfma<<<2048, 256, 0, stream>>>(gd, gdfn_out_w, out);
}

// Round 5
// 368.692 us; speedup vs baseline: 4.7140x; 2.9757x over previous
//
#include <hip/hip_runtime.h>
#include <hip/hip_bf16.h>
#include <math.h>

#define HWn 65536
#define Hh 256
#define Wd 256
#define Bb 2
#define Cc 64
#define NHh 8
#define HIDc 170
#define PXN 131072   // Bb * HWn

typedef __hip_bfloat16 bf16;
typedef __attribute__((ext_vector_type(8))) short short8;
typedef __attribute__((ext_vector_type(4))) short s16x4;
typedef __attribute__((ext_vector_type(4))) float f32x4;

__device__ inline float b2f(short u) {
    unsigned int x = ((unsigned int)(unsigned short)u) << 16;
    return __uint_as_float(x);
}
__device__ inline short f2b(float f) {
    __hip_bfloat16 h = __float2bfloat16(f);
    return *reinterpret_cast<short*>(&h);
}
__device__ inline int remap_row(int c, int remap) {
    if (!remap) return c;
    return c < 170 ? c : (c >= 176 && c < 346 ? c - 6 : -1);
}

// ---------- zero small scratch ----------
__global__ void zero_k(float* p, int n) {
    for (int i = threadIdx.x; i < n; i += 256) p[i] = 0.f;
}

// ---------- LayerNorm over 64 ch: f32 [b][c][hw] -> bf16 chunked [8][PXN][8] ----------
__global__ __launch_bounds__(256, 2)
void ln_px(const float* __restrict__ x, const float* __restrict__ w,
           const float* __restrict__ bia, bf16* __restrict__ out) {
    int idx = blockIdx.x * 256 + threadIdx.x;
    int b = idx >> 16, p = idx & 65535;
    const float* xp = x + (size_t)b * 64 * HWn + p;
    float f[64];
    float s = 0.f;
#pragma unroll
    for (int c = 0; c < 64; c++) { f[c] = xp[(size_t)c * HWn]; s += f[c]; }
    float mu = s * (1.f / 64.f);
    float s2 = 0.f;
#pragma unroll
    for (int c = 0; c < 64; c++) { float d = f[c] - mu; s2 += d * d; }
    float inv = rsqrtf(s2 * (1.f / 64.f) + 1e-5f);
#pragma unroll
    for (int c8 = 0; c8 < 8; c8++) {
        short8 o;
#pragma unroll
        for (int e = 0; e < 8; e++) {
            int c = c8 * 8 + e;
            o[e] = f2b((f[c] - mu) * inv * w[c] + bia[c]);
        }
        *reinterpret_cast<short8*>(out + ((size_t)c8 * PXN + idx) * 8) = o;
    }
}

// ---------- 1x1 conv via MFMA, chunked in/out. Wave loops over strips (B reused) ----------
__global__ __launch_bounds__(256)
void conv1x1_mfma(const bf16* __restrict__ in, const float* __restrict__ w,
                  int nstrips, int remap, bf16* __restrict__ out) {
    int lane = threadIdx.x & 63, wid = threadIdx.x >> 6;
    int r16 = lane & 15, grp = lane >> 4;
    size_t px0 = (size_t)blockIdx.x * 64;
    const bf16* bp0 = in + ((size_t)grp * PXN + px0 + r16) * 8;
    const bf16* bp1 = in + (((size_t)grp + 4) * PXN + px0 + r16) * 8;
    short8 b0[4], b1[4];
#pragma unroll
    for (int s = 0; s < 4; s++) {
        b0[s] = *reinterpret_cast<const short8*>(bp0 + s * 128);
        b1[s] = *reinterpret_cast<const short8*>(bp1 + s * 128);
    }
    for (int si = wid; si < nstrips; si += 4) {
        int co = si * 16 + r16;
        int row = remap_row(co, remap);
        short8 a0, a1;
        if (row >= 0) {
            const float* wr = w + (size_t)row * 64 + grp * 8;
#pragma unroll
            for (int e = 0; e < 8; e++) { a0[e] = f2b(wr[e]); a1[e] = f2b(wr[32 + e]); }
        } else {
#pragma unroll
            for (int e = 0; e < 8; e++) { a0[e] = 0; a1[e] = 0; }
        }
        int ochunk = si * 2 + (grp >> 1);
        int osub = (grp & 1) * 4;
#pragma unroll
        for (int s = 0; s < 4; s++) {
            f32x4 acc = {0.f, 0.f, 0.f, 0.f};
            acc = __builtin_amdgcn_mfma_f32_16x16x32_bf16(a0, b0[s], acc, 0, 0, 0);
            acc = __builtin_amdgcn_mfma_f32_16x16x32_bf16(a1, b1[s], acc, 0, 0, 0);
            size_t px = px0 + s * 16 + r16;
            s16x4 o;
#pragma unroll
            for (int j = 0; j < 4; j++) o[j] = f2b(acc[j]);
            *reinterpret_cast<s16x4*>(out + ((size_t)ochunk * PXN + px) * 8 + osub) = o;
        }
    }
}

// ---------- depthwise 3x3 on chunked layout: block = chunk x rowgroup(8 rows) ----------
__global__ __launch_bounds__(256, 2)
void dwconv3_ch(const bf16* __restrict__ in, const float* __restrict__ w,
                int remap, bf16* __restrict__ out) {
    __shared__ float wl[72];
    int chunk = blockIdx.x >> 6, rg = blockIdx.x & 63;
    int t = threadIdx.x;
    if (t < 72) {
        int c = chunk * 8 + t / 9;
        int k9 = t - (t / 9) * 9;
        int row = remap_row(c, remap);
        wl[t] = (row >= 0) ? w[row * 9 + k9] : 0.f;
    }
    __syncthreads();
    int ty = t >> 5;
    int tx8 = (t & 31) << 3;
    int gy = rg * 8 + ty;              // 0..511
    int b = gy >> 8, y = gy & 255;
    const bf16* cbase = in + ((size_t)chunk * PXN + (size_t)b * 65536) * 8;
    float acc[8][8];
#pragma unroll
    for (int j = 0; j < 8; j++)
#pragma unroll
        for (int e = 0; e < 8; e++) acc[j][e] = 0.f;
#pragma unroll
    for (int dy = 0; dy < 3; dy++) {
        int ys = y + dy - 1;
        if (ys < 0 || ys >= 256) continue;
        const bf16* rbase = cbase + (size_t)ys * 256 * 8;
        short8 rv[10];
        if (tx8 > 0) rv[0] = *reinterpret_cast<const short8*>(rbase + (tx8 - 1) * 8);
        else { short8 z; for (int e = 0; e < 8; e++) z[e] = 0; rv[0] = z; }
#pragma unroll
        for (int i = 0; i < 8; i++)
            rv[i + 1] = *reinterpret_cast<const short8*>(rbase + (tx8 + i) * 8);
        if (tx8 + 8 < 256) rv[9] = *reinterpret_cast<const short8*>(rbase + (tx8 + 8) * 8);
        else { short8 z; for (int e = 0; e < 8; e++) z[e] = 0; rv[9] = z; }
#pragma unroll
        for (int dx = 0; dx < 3; dx++) {
#pragma unroll
            for (int j = 0; j < 8; j++) {
                short8 v = rv[j + dx];
#pragma unroll
                for (int e = 0; e < 8; e++)
                    acc[j][e] = fmaf(wl[e * 9 + dy * 3 + dx], b2f(v[e]), acc[j][e]);
            }
        }
    }
    bf16* obase = out + ((size_t)chunk * PXN + (size_t)b * 65536 + (size_t)y * 256) * 8;
#pragma unroll
    for (int j = 0; j < 8; j++) {
        short8 o;
#pragma unroll
        for (int e = 0; e < 8; e++) o[e] = f2b(acc[j][e]);
        *reinterpret_cast<short8*>(obase + (tx8 + j) * 8) = o;
    }
}

// ---------- attention dots + row norms (chunked) ----------
__global__ __launch_bounds__(256, 2)
void attn_dots_px(const bf16* __restrict__ txd, const bf16* __restrict__ tyd,
                  float* __restrict__ G, float* __restrict__ NA,
                  float* __restrict__ NB) {
    int which = blockIdx.z;
    int bh = blockIdx.y;
    int b = bh >> 3, h = bh & 7;
    const bf16* Aq = (which == 0 ? tyd : txd) + ((size_t)h * PXN + (size_t)b * 65536) * 8;
    const bf16* Bk = (which == 0 ? txd : tyd) + (((size_t)8 + h) * PXN + (size_t)b * 65536) * 8;
    float acc[8][8], na[8], nb[8];
#pragma unroll
    for (int c = 0; c < 8; c++) {
        na[c] = 0.f; nb[c] = 0.f;
#pragma unroll
        for (int d = 0; d < 8; d++) acc[c][d] = 0.f;
    }
    int per = 65536 / gridDim.x;
    int n0 = blockIdx.x * per;
    for (int n = n0 + threadIdx.x; n < n0 + per; n += 256) {
        short8 q8 = *reinterpret_cast<const short8*>(Aq + (size_t)n * 8);
        short8 k8 = *reinterpret_cast<const short8*>(Bk + (size_t)n * 8);
        float av[8], bv[8];
#pragma unroll
        for (int i = 0; i < 8; i++) { av[i] = b2f(q8[i]); bv[i] = b2f(k8[i]); }
#pragma unroll
        for (int c = 0; c < 8; c++) na[c] = fmaf(av[c], av[c], na[c]);
#pragma unroll
        for (int d = 0; d < 8; d++) nb[d] = fmaf(bv[d], bv[d], nb[d]);
#pragma unroll
        for (int c = 0; c < 8; c++)
#pragma unroll
            for (int d = 0; d < 8; d++) acc[c][d] = fmaf(av[c], bv[d], acc[c][d]);
    }
    size_t gbase = (((size_t)which * Bb + b) * 8 + h);
    float* Gp = G + gbase * 64;
#pragma unroll
    for (int c = 0; c < 8; c++)
#pragma unroll
        for (int d = 0; d < 8; d++) {
            float s = acc[c][d];
#pragma unroll
            for (int m = 1; m < 64; m <<= 1) s += __shfl_xor(s, m);
            if ((threadIdx.x & 63) == 0) atomicAdd(&Gp[c * 8 + d], s);
        }
#pragma unroll
    for (int c = 0; c < 8; c++) {
        float s = na[c];
#pragma unroll
        for (int m = 1; m < 64; m <<= 1) s += __shfl_xor(s, m);
        if ((threadIdx.x & 63) == 0) atomicAdd(&NA[gbase * 8 + c], s);
        float s2 = nb[c];
#pragma unroll
        for (int m = 1; m < 64; m <<= 1) s2 += __shfl_xor(s2, m);
        if ((threadIdx.x & 63) == 0) atomicAdd(&NB[gbase * 8 + c], s2);
    }
}

// ---------- tiny softmax with l2norm scaling and temperature ----------
__global__ void attn_softmax(const float* __restrict__ G, const float* __restrict__ NA,
                             const float* __restrict__ NB, const float* __restrict__ temp,
                             float* __restrict__ A) {
    int t = threadIdx.x;
    int h = (t >> 3) & 7;
    int c = t & 7;
    size_t rbase = t >> 3;
    const float* Gp = G + rbase * 64 + c * 8;
    float an = fmaxf(sqrtf(NA[rbase * 8 + c]), 1e-12f);
    float tm = temp[h];
    float vals[8];
    float mx = -1e30f;
#pragma unroll
    for (int d = 0; d < 8; d++) {
        float bn = fmaxf(sqrtf(NB[rbase * 8 + d]), 1e-12f);
        float v = Gp[d] / (an * bn) * tm;
        vals[d] = v;
        mx = fmaxf(mx, v);
    }
    float se = 0.f;
#pragma unroll
    for (int d = 0; d < 8; d++) { vals[d] = expf(vals[d] - mx); se += vals[d]; }
    float inv = 1.f / se;
    float* Ap = A + rbase * 64 + c * 8;
#pragma unroll
    for (int d = 0; d < 8; d++) Ap[d] = vals[d] * inv;
}

// ---------- cross attention + residual + LN2 (chunked v) ----------
__global__ __launch_bounds__(256, 2)
void cross_ln2_px(const float* __restrict__ x, const bf16* __restrict__ txd,
                  const bf16* __restrict__ tyd, const float* __restrict__ A,
                  const float* __restrict__ ln2w, const float* __restrict__ ln2b,
                  float* __restrict__ out, bf16* __restrict__ xn2) {
    int idx = blockIdx.x * 256 + threadIdx.x;
    int b = idx >> 16, p = idx & 65535;
    __shared__ float a1[512], a2[512];
    for (int i = threadIdx.x; i < 512; i += 256) {
        a1[i] = A[(size_t)b * 512 + i];
        a2[i] = A[((size_t)2 + b) * 512 + i];
    }
    __syncthreads();
    float o[64];
    const float* xp = x + (size_t)b * 64 * HWn + p;
#pragma unroll
    for (int c = 0; c < 64; c++) o[c] = xp[(size_t)c * HWn];
#pragma unroll
    for (int h = 0; h < 8; h++) {
        short8 v8 = *reinterpret_cast<const short8*>(txd + (((size_t)16 + h) * PXN + idx) * 8);
        short8 w8 = *reinterpret_cast<const short8*>(tyd + (((size_t)16 + h) * PXN + idx) * 8);
        float v[8], v1[8];
#pragma unroll
        for (int d = 0; d < 8; d++) { v[d] = b2f(v8[d]); v1[d] = b2f(w8[d]); }
#pragma unroll
        for (int ci = 0; ci < 8; ci++) {
            float s = 0.f;
            const float* r1 = a1 + h * 64 + ci * 8;
            const float* r2 = a2 + h * 64 + ci * 8;
#pragma unroll
            for (int d = 0; d < 8; d++) s += r1[d] * v[d] + r2[d] * v1[d];
            o[h * 8 + ci] += s;
        }
    }
    float* op = out + (size_t)b * 64 * HWn + p;
    float s = 0.f;
#pragma unroll
    for (int c = 0; c < 64; c++) { op[(size_t)c * HWn] = o[c]; s += o[c]; }
    float mu = s * (1.f / 64.f);
    float s2 = 0.f;
#pragma unroll
    for (int c = 0; c < 64; c++) { float d = o[c] - mu; s2 += d * d; }
    float inv = rsqrtf(s2 * (1.f / 64.f) + 1e-5f);
#pragma unroll
    for (int c8 = 0; c8 < 8; c8++) {
        short8 o8;
#pragma unroll
        for (int e = 0; e < 8; e++) {
            int c = c8 * 8 + e;
            o8[e] = f2b((o[c] - mu) * inv * ln2w[c] + ln2b[c]);
        }
        *reinterpret_cast<short8*>(xn2 + ((size_t)c8 * PXN + idx) * 8) = o8;
    }
}

// ---------- GDFN out: stage t=gelu(g1)*g2 in LDS (stride 180), MFMA 170->64, += out ----------
__global__ __launch_bounds__(256)
void gdfn_out_mfma(const bf16* __restrict__ gd, const float* __restrict__ wout,
                   float* __restrict__ out) {
    __shared__ short tl[64 * 180 + 64];
    int tid = threadIdx.x;
    size_t px0 = (size_t)blockIdx.x * 64;
    for (int i = tid; i < 64 * 22; i += 256) {
        int px = i & 63, ch = i >> 6;
        short8 g1 = *reinterpret_cast<const short8*>(gd + ((size_t)ch * PXN + px0 + px) * 8);
        short8 g2 = *reinterpret_cast<const short8*>(gd + (((size_t)22 + ch) * PXN + px0 + px) * 8);
        short8 tt;
#pragma unroll
        for (int e = 0; e < 8; e++) {
            float a = b2f(g1[e]);
            float gg = b2f(g2[e]);
            tt[e] = f2b(a * 0.5f * (1.f + erff(a * 0.70710678118654752f)) * gg);
        }
        *reinterpret_cast<short8*>(&tl[px * 180 + ch * 8]) = tt;
    }
    if (tid < 64) {                      // zero per-row stride pad + tail pad
        tl[tid * 180 + 176] = 0; tl[tid * 180 + 177] = 0;
        tl[tid * 180 + 178] = 0; tl[tid * 180 + 179] = 0;
        tl[64 * 180 + tid] = 0;
    }
    __syncthreads();
    int lane = tid & 63, wid = tid >> 6;
    int r16 = lane & 15, grp = lane >> 4;
    int co = wid * 16 + r16;
    short8 af[6];
#pragma unroll
    for (int kc = 0; kc < 6; kc++) {
#pragma unroll
        for (int e = 0; e < 8; e++) {
            int k = kc * 32 + grp * 8 + e;
            af[kc][e] = (k < 170) ? f2b(wout[(size_t)co * 170 + k]) : (short)0;
        }
    }
#pragma unroll
    for (int s = 0; s < 4; s++) {
        f32x4 acc = {0.f, 0.f, 0.f, 0.f};
        const short* tp = &tl[(s * 16 + r16) * 180 + grp * 8];
#pragma unroll
        for (int kc = 0; kc < 6; kc++) {
            short8 bv = *reinterpret_cast<const short8*>(tp + kc * 32);
            acc = __builtin_amdgcn_mfma_f32_16x16x32_bf16(af[kc], bv, acc, 0, 0, 0);
        }
        size_t px = px0 + s * 16 + r16;
        int b = (int)(px >> 16);
        int p = (int)(px & 65535);
        float* op = out + (size_t)b * 64 * HWn + (size_t)(wid * 16 + grp * 4) * HWn + p;
#pragma unroll
        for (int j = 0; j < 4; j++) op[(size_t)j * HWn] += acc[j];
    }
}

extern "C" void kernel_launch(void* const* d_in, const int* in_sizes, int n_in,
                              void* d_out, int out_size, void* d_ws, size_t ws_size,
                              hipStream_t stream) {
    const float* x = (const float*)d_in[0];
    const float* y = (const float*)d_in[1];
    const float* ln11_w = (const float*)d_in[2];
    const float* ln11_b = (const float*)d_in[3];
    const float* ln12_w = (const float*)d_in[4];
    const float* ln12_b = (const float*)d_in[5];
    const float* ln2_w = (const float*)d_in[6];
    const float* ln2_b = (const float*)d_in[7];
    const float* qkv_w = (const float*)d_in[8];
    const float* qkv_dw = (const float*)d_in[9];
    const float* temp = (const float*)d_in[10];
    const float* gdfn_in_w = (const float*)d_in[11];
    const float* gdfn_dw = (const float*)d_in[12];
    const float* gdfn_out_w = (const float*)d_in[13];
    float* out = (float*)d_out;

    char* wsb = (char*)d_ws;
    float* G = (float*)wsb;            // 2048
    float* NA = G + 2048;              // 256
    float* NB = NA + 256;              // 256
    float* Amat = NB + 256;            // 2048
    bf16* hp = (bf16*)(wsb + 18944);
    bf16* xn  = hp;                    // 8 chunks  [8][PXN][8]
    bf16* yn  = hp + (size_t)8388608;  // 8 chunks
    bf16* tx  = hp + (size_t)16777216; // 24 chunks
    bf16* txd = hp + (size_t)41943040; // 24 chunks
    bf16* tyd = hp + (size_t)67108864; // 24 chunks (end 92,274,688)
    bf16* g   = hp + (size_t)8388608;  // 44 chunks, overlays yn/tx/txd (dead)
    bf16* gd  = hp + (size_t)54525952; // 44 chunks, overlays tyd (dead)

    zero_k<<<1, 256, 0, stream>>>(G, 2560);

    ln_px<<<512, 256, 0, stream>>>(x, ln11_w, ln11_b, xn);
    ln_px<<<512, 256, 0, stream>>>(y, ln12_w, ln12_b, yn);

    conv1x1_mfma<<<2048, 256, 0, stream>>>(xn, qkv_w, 12, 0, tx);
    dwconv3_ch<<<24 * 64, 256, 0, stream>>>(tx, qkv_dw, 0, txd);
    conv1x1_mfma<<<2048, 256, 0, stream>>>(yn, qkv_w, 12, 0, tx);
    dwconv3_ch<<<24 * 64, 256, 0, stream>>>(tx, qkv_dw, 0, tyd);

    attn_dots_px<<<dim3(16, 16, 2), 256, 0, stream>>>(txd, tyd, G, NA, NB);
    attn_softmax<<<1, 256, 0, stream>>>(G, NA, NB, temp, Amat);

    cross_ln2_px<<<512, 256, 0, stream>>>(x, txd, tyd, Amat, ln2_w, ln2_b, out, xn);

    conv1x1_mfma<<<2048, 256, 0, stream>>>(xn, gdfn_in_w, 22, 1, g);
    dwconv3_ch<<<44 * 64, 256, 0, stream>>>(g, gdfn_dw, 1, gd);
    gdfn_out_mfma<<<2048, 256, 0, stream>>>(gd, gdfn_out_w, out);
}